// Round 3
// baseline (1001.635 us; speedup 1.0000x reference)
//
#include <hip/hip_runtime.h>
#include <hip/hip_bf16.h>

typedef __hip_bfloat16 bf16;
typedef __attribute__((ext_vector_type(8))) short bh8;   // 8 bf16 (MFMA A/B frag)
typedef __attribute__((ext_vector_type(4))) float f4;    // MFMA C/D frag

#define TOKENS 200704   // 16*112*112 = 4096 windows * 49
#define CDIM   192

__device__ __forceinline__ void gload16(const bf16* g, bf16* l) {
    __builtin_amdgcn_global_load_lds((const __attribute__((address_space(1))) void*)g,
                                     (__attribute__((address_space(3))) void*)l,
                                     16, 0, 0);
}

__device__ __forceinline__ void stv(float* p, float v) { *p = v; }
__device__ __forceinline__ void stv(bf16* p, float v)  { *p = __float2bfloat16(v); }

// ---- fp32 -> bf16 weight conversion ----
__global__ void cvt_kernel(const float* __restrict__ s, bf16* __restrict__ d, int n) {
    int i = blockIdx.x * 256 + threadIdx.x;
    if (i < n) d[i] = __float2bfloat16(s[i]);
}

// ---- bias precompute: biasg[h][i][j] = rpb_table[rpi[i*49+j]][h] (fp32) ----
__global__ void bias_kernel(const int* __restrict__ rpi, const float* __restrict__ tab,
                            float* __restrict__ bg) {
    int idx = blockIdx.x * 256 + threadIdx.x;
    if (idx < 6 * 2401) {
        int h = idx / 2401, ij = idx - h * 2401;
        bg[idx] = tab[rpi[ij] * 6 + h];
    }
}

// ---- LayerNorm (fp32 in, bf16 out); GATHER=1 adds shift(-3,-3) + window partition ----
template<int GATHER>
__global__ __launch_bounds__(256)
void ln_kernel(const float* __restrict__ src, const float* __restrict__ gw,
               const float* __restrict__ bw, bf16* __restrict__ dst) {
    const int lane = threadIdx.x & 63;
    const int gwv  = (blockIdx.x * 256 + threadIdx.x) >> 6;
    const int nwv  = (gridDim.x * 256) >> 6;
    const float g0 = gw[lane], g1 = gw[lane + 64], g2 = gw[lane + 128];
    const float b0 = bw[lane], b1 = bw[lane + 64], b2 = bw[lane + 128];
    for (int row = gwv; row < TOKENS; row += nwv) {
        const float* p;
        if (GATHER) {
            int win = row / 49, n = row - win * 49;
            int b = win >> 8, rem = win & 255;
            int hs = (rem >> 4) * 7 + n / 7;
            int ws = (rem & 15) * 7 + n % 7;
            int hh = hs + 3; if (hh >= 112) hh -= 112;
            int ww = ws + 3; if (ww >= 112) ww -= 112;
            p = src + ((size_t)((b * 112 + hh) * 112 + ww)) * CDIM;
        } else {
            p = src + (size_t)row * CDIM;
        }
        float v0 = p[lane], v1 = p[lane + 64], v2 = p[lane + 128];
        float s = v0 + v1 + v2;
        float q = v0 * v0 + v1 * v1 + v2 * v2;
        #pragma unroll
        for (int o = 32; o; o >>= 1) { s += __shfl_xor(s, o, 64); q += __shfl_xor(q, o, 64); }
        float mean = s * (1.f / 192.f);
        float var  = q * (1.f / 192.f) - mean * mean;
        float rstd = rsqrtf(var + 1e-5f);
        bf16* d = dst + (size_t)row * CDIM;
        d[lane]       = __float2bfloat16((v0 - mean) * rstd * g0 + b0);
        d[lane + 64]  = __float2bfloat16((v1 - mean) * rstd * g1 + b1);
        d[lane + 128] = __float2bfloat16((v2 - mean) * rstd * g2 + b2);
    }
}

// ---- GEMM: C[M,N] = A[M,K] @ W[N,K]^T + bias (A,W bf16; bias/res fp32) ----
// EPI: 0 = plain->bf16 (qkv), 1 = scatter+residual->fp32 (proj)
// BM=128, BN=192(or 576 grid.x), BK=32; 4 waves, each 64x96 (4x6 frags 16x16x32)
template<int EPI, typename OutT>
__global__ __launch_bounds__(256)
void gemm_bt(const bf16* __restrict__ A, const bf16* __restrict__ W,
             const float* __restrict__ bias, OutT* out,
             const float* res, int N, int K) {
    __shared__ __align__(16) bf16 As[128 * 32];
    __shared__ __align__(16) bf16 Bs[192 * 32];
    const int tid = threadIdx.x, wid = tid >> 6, lane = tid & 63;
    const int mbase = blockIdx.y * 128, nbase = blockIdx.x * 192;
    const int wm = wid >> 1, wn = wid & 1;
    const int r = lane & 15, ko = (lane >> 4) * 8;
    const bf16* Ab = A + (size_t)mbase * K;
    const bf16* Wb = W + (size_t)nbase * K;
    f4 acc[4][6] = {};
    const int cbase = wid * 64 + lane;
    for (int k0 = 0; k0 < K; k0 += 32) {
        #pragma unroll
        for (int p = 0; p < 2; ++p) {   // A tile: 128x32 = 512 chunks of 16B
            int ci = p * 256 + cbase;
            gload16(Ab + (size_t)(ci >> 2) * K + (k0 + ((ci & 3) << 3)),
                    &As[(p * 256 + wid * 64) * 8]);
        }
        #pragma unroll
        for (int p = 0; p < 3; ++p) {   // B tile: 192x32 = 768 chunks of 16B
            int ci = p * 256 + cbase;
            gload16(Wb + (size_t)(ci >> 2) * K + (k0 + ((ci & 3) << 3)),
                    &Bs[(p * 256 + wid * 64) * 8]);
        }
        __syncthreads();
        bh8 af[4], bfr[6];
        #pragma unroll
        for (int i = 0; i < 4; ++i)
            af[i] = *(const bh8*)&As[(wm * 64 + i * 16 + r) * 32 + ko];
        #pragma unroll
        for (int j = 0; j < 6; ++j)
            bfr[j] = *(const bh8*)&Bs[(wn * 96 + j * 16 + r) * 32 + ko];
        #pragma unroll
        for (int i = 0; i < 4; ++i)
            #pragma unroll
            for (int j = 0; j < 6; ++j)
                acc[i][j] = __builtin_amdgcn_mfma_f32_16x16x32_bf16(af[i], bfr[j], acc[i][j], 0, 0, 0);
        __syncthreads();
    }
    // epilogue: C/D frag layout col = lane&15, row = (lane>>4)*4 + reg
    const int cr = lane >> 4, cc = lane & 15;
    #pragma unroll
    for (int i = 0; i < 4; ++i) {
        size_t dstRow[4];
        #pragma unroll
        for (int rr = 0; rr < 4; ++rr) {
            int row = mbase + wm * 64 + i * 16 + cr * 4 + rr;
            if constexpr (EPI == 1) {
                int win = row / 49, n = row - win * 49;
                int b = win >> 8, rem = win & 255;
                int hs = (rem >> 4) * 7 + n / 7;
                int ws = (rem & 15) * 7 + n % 7;
                int hh = hs + 3; if (hh >= 112) hh -= 112;
                int ww = ws + 3; if (ww >= 112) ww -= 112;
                dstRow[rr] = ((size_t)((b * 112 + hh) * 112 + ww)) * CDIM;
            } else {
                dstRow[rr] = (size_t)row * N;
            }
        }
        #pragma unroll
        for (int j = 0; j < 6; ++j) {
            int ncol = nbase + wn * 96 + j * 16 + cc;
            float bv = bias[ncol];
            #pragma unroll
            for (int rr = 0; rr < 4; ++rr) {
                float v = acc[i][j][rr] + bv;
                size_t di = dstRow[rr] + ncol;
                if constexpr (EPI == 1) v += res[di];
                stv(&out[di], v);
            }
        }
    }
}

// ---- attention: one wave per (local window, head); in-register softmax ----
__global__ __launch_bounds__(256)
void attn_kernel(const bf16* __restrict__ qkv, const float* __restrict__ mask,
                 const float* __restrict__ biasg, bf16* __restrict__ out, int woff) {
    __shared__ float kv[4][2][49][32];   // 50176 B
    const int wid = threadIdx.x >> 6, lane = threadIdx.x & 63;
    const int task = blockIdx.x * 4 + wid;
    const int win = task / 6;                 // local window within chunk
    const int head = task - win * 6;
    const bf16* base = qkv + (size_t)win * 49 * 576 + head * 32;
    for (int idx = lane; idx < 49 * 32; idx += 64) {
        int j = idx >> 5, d = idx & 31;
        kv[wid][0][j][d] = __bfloat162float(base[j * 576 + 192 + d]);  // K
        kv[wid][1][j][d] = __bfloat162float(base[j * 576 + 384 + d]);  // V
    }
    __syncthreads();
    const int i = lane < 49 ? lane : 48;
    float q[32];
    #pragma unroll
    for (int d = 0; d < 32; ++d)
        q[d] = __bfloat162float(base[i * 576 + d]) * 0.17677669529663689f;  // 1/sqrt(32)
    const float* bg = biasg + head * 2401 + i * 49;
    const float* mk = mask + (size_t)((win + woff) & 255) * 2401 + i * 49;
    float s[49];
    float mx = -1e30f;
    #pragma unroll
    for (int j = 0; j < 49; ++j) {
        float a = 0.f;
        #pragma unroll
        for (int d = 0; d < 32; ++d) a += q[d] * kv[wid][0][j][d];
        a += bg[j] + mk[j];
        s[j] = a;
        mx = fmaxf(mx, a);
    }
    float sum = 0.f;
    #pragma unroll
    for (int j = 0; j < 49; ++j) { s[j] = __expf(s[j] - mx); sum += s[j]; }
    const float inv = 1.f / sum;
    float o[32];
    #pragma unroll
    for (int d = 0; d < 32; ++d) o[d] = 0.f;
    #pragma unroll
    for (int j = 0; j < 49; ++j) {
        float p = s[j] * inv;
        #pragma unroll
        for (int d = 0; d < 32; ++d) o[d] += p * kv[wid][1][j][d];
    }
    if (lane < 49) {
        bf16* op = out + ((size_t)win * 49 + lane) * CDIM + head * 32;
        #pragma unroll
        for (int d = 0; d < 32; ++d) op[d] = __float2bfloat16(o[d]);
    }
}

// ---- fused MLP: out = x1 + fc2(gelu(fc1(ln2out))) ; in-place RMW on out (fp32) ----
// Per block: 128 rows. A (128x192) staged once in LDS as 6 k-slices.
// 12 chunks of 64 fc1-outputs: GEMM1(128x64xK192) -> gelu -> Hs -> GEMM2 accumulate (128x192xK64).
// Weights read as 16B lane fragments straight from global (L2-resident, ~1.2 MB total).
__global__ __launch_bounds__(256, 2)
void mlp_kernel(const bf16* __restrict__ Aht, const bf16* __restrict__ w1,
                const float* __restrict__ b1, const bf16* __restrict__ w2,
                const float* __restrict__ b2, float* out) {
    __shared__ __align__(16) bf16 As[6][128][32];   // 49152 B
    __shared__ __align__(16) bf16 Hs[2][128][32];   // 16384 B
    const int tid = threadIdx.x, wid = tid >> 6, lane = tid & 63;
    const int mbase = blockIdx.x * 128;
    const int wm = wid >> 1, wn = wid & 1;
    const int r = lane & 15, ko = (lane >> 4) * 8;
    const int cr = lane >> 4, cc = lane & 15;
    const bf16* Ab = Aht + (size_t)mbase * 192;
    // stage A tile: 3072 16B chunks; lds chunk l holds global (row=(l&511)>>2, ks=l>>9, gg=l&3)
    #pragma unroll
    for (int it = 0; it < 12; ++it) {
        int l = it * 256 + wid * 64 + lane;
        int ks = l >> 9, rem = l & 511, row = rem >> 2, gg = rem & 3;
        gload16(Ab + row * 192 + ks * 32 + gg * 8,
                &As[0][0][0] + (size_t)(it * 256 + wid * 64) * 8);
    }
    __syncthreads();
    f4 acc2[4][6] = {};
    for (int c = 0; c < 12; ++c) {
        const int cb = c * 64;
        f4 acc1[4][2] = {};
        #pragma unroll
        for (int ks = 0; ks < 6; ++ks) {
            bh8 af[4], bfr[2];
            #pragma unroll
            for (int i = 0; i < 4; ++i) af[i] = *(const bh8*)&As[ks][wm * 64 + i * 16 + r][ko];
            #pragma unroll
            for (int jn = 0; jn < 2; ++jn)
                bfr[jn] = *(const bh8*)&w1[(size_t)(cb + wn * 32 + jn * 16 + r) * 192 + ks * 32 + ko];
            #pragma unroll
            for (int i = 0; i < 4; ++i)
                #pragma unroll
                for (int jn = 0; jn < 2; ++jn)
                    acc1[i][jn] = __builtin_amdgcn_mfma_f32_16x16x32_bf16(af[i], bfr[jn], acc1[i][jn], 0, 0, 0);
        }
        __syncthreads();   // previous chunk's GEMM2 reads of Hs complete
        #pragma unroll
        for (int i = 0; i < 4; ++i)
            #pragma unroll
            for (int jn = 0; jn < 2; ++jn)
                #pragma unroll
                for (int rr = 0; rr < 4; ++rr) {
                    int row = wm * 64 + i * 16 + cr * 4 + rr;
                    int col = jn * 16 + cc;
                    float v = acc1[i][jn][rr] + b1[cb + wn * 32 + col];
                    float u = v * (0.7978845608f + 0.0356774081f * v * v);  // sqrt(2/pi)*(v+0.044715v^3)
                    float e = __expf(2.f * u);
                    float t = 1.f - 2.f / (e + 1.f);                        // tanh(u)
                    Hs[wn][row][col] = __float2bfloat16(0.5f * v * (1.f + t));
                }
        __syncthreads();
        #pragma unroll
        for (int ks = 0; ks < 2; ++ks) {
            bh8 af[4], bfr[6];
            #pragma unroll
            for (int i = 0; i < 4; ++i) af[i] = *(const bh8*)&Hs[ks][wm * 64 + i * 16 + r][ko];
            #pragma unroll
            for (int j = 0; j < 6; ++j)
                bfr[j] = *(const bh8*)&w2[(size_t)(wn * 96 + j * 16 + r) * 768 + cb + ks * 32 + ko];
            #pragma unroll
            for (int i = 0; i < 4; ++i)
                #pragma unroll
                for (int j = 0; j < 6; ++j)
                    acc2[i][j] = __builtin_amdgcn_mfma_f32_16x16x32_bf16(af[j == 0 ? i : i], bfr[j], acc2[i][j], 0, 0, 0);
        }
        __syncthreads();   // protect Hs before next chunk overwrites
    }
    #pragma unroll
    for (int i = 0; i < 4; ++i)
        #pragma unroll
        for (int j = 0; j < 6; ++j) {
            int ncol = wn * 96 + j * 16 + cc;
            float bv = b2[ncol];
            #pragma unroll
            for (int rr = 0; rr < 4; ++rr) {
                size_t idx = (size_t)(mbase + wm * 64 + i * 16 + cr * 4 + rr) * 192 + ncol;
                out[idx] = acc2[i][j][rr] + bv + out[idx];
            }
        }
}

extern "C" void kernel_launch(void* const* d_in, const int* in_sizes, int n_in,
                              void* d_out, int out_size, void* d_ws, size_t ws_size,
                              hipStream_t stream) {
    const float* x     = (const float*)d_in[0];
    const float* mask  = (const float*)d_in[1];
    const int*   rpi   = (const int*)d_in[2];
    const float* rpb   = (const float*)d_in[3];
    const float* n1g   = (const float*)d_in[4];
    const float* n1b   = (const float*)d_in[5];
    const float* qkvw  = (const float*)d_in[6];
    const float* qkvb  = (const float*)d_in[7];
    const float* projw = (const float*)d_in[8];
    const float* projb = (const float*)d_in[9];
    const float* n2g   = (const float*)d_in[10];
    const float* n2b   = (const float*)d_in[11];
    const float* fc1w  = (const float*)d_in[12];
    const float* fc1b  = (const float*)d_in[13];
    const float* fc2w  = (const float*)d_in[14];
    const float* fc2b  = (const float*)d_in[15];

    // Workspace layout (peak ~136 MB with 1024-window chunks; adaptive down to ~85 MB):
    //  [0, 77,070,336)          attno (bf16) -> later ln2-out hbuf (bf16)
    //  [77,070,336, 77,131,776) biasg fp32 (57,624 used)
    //  [77,131,776, ...)        bf16 weights: wq 221,184 | wp 73,728 | w1 294,912 | w2 294,912
    //  [78,016,512, ...)        qbuf: qkv chunk, cw*49*576*2 bytes
    char* ws = (char*)d_ws;
    bf16*  attno  = (bf16*)ws;
    bf16*  hbuf   = (bf16*)ws;
    float* biasg  = (float*)(ws + 77070336);
    bf16*  wq     = (bf16*)(ws + 77131776);
    bf16*  wp     = (bf16*)(ws + 77352960);
    bf16*  w1     = (bf16*)(ws + 77426688);
    bf16*  w2     = (bf16*)(ws + 77721600);
    bf16*  qbuf   = (bf16*)(ws + 78016512);
    bf16*  xw     = (bf16*)d_out;    // LN1 out lives in d_out until proj overwrites it
    float* x1     = (float*)d_out;

    // adaptive chunk size (windows); deterministic given ws_size
    int cw = 1024;
    while (cw > 128 && 78016512ull + (size_t)cw * 56448 > ws_size) cw >>= 1;
    const int nchunks = 4096 / cw;

    cvt_kernel<<<432, 256, 0, stream>>>(qkvw, wq, 110592);
    cvt_kernel<<<144, 256, 0, stream>>>(projw, wp, 36864);
    cvt_kernel<<<576, 256, 0, stream>>>(fc1w, w1, 147456);
    cvt_kernel<<<576, 256, 0, stream>>>(fc2w, w2, 147456);
    bias_kernel<<<57, 256, 0, stream>>>(rpi, rpb, biasg);

    ln_kernel<1><<<2048, 256, 0, stream>>>(x, n1g, n1b, xw);
    for (int c = 0; c < nchunks; ++c) {
        const size_t tok0 = (size_t)c * cw * 49;
        gemm_bt<0, bf16><<<dim3(3, cw * 49 / 128), 256, 0, stream>>>(
            xw + tok0 * 192, wq, qkvb, qbuf, nullptr, 576, 192);
        attn_kernel<<<cw * 6 / 4, 256, 0, stream>>>(
            qbuf, mask, biasg, attno + tok0 * 192, c * cw);
    }
    gemm_bt<1, float><<<dim3(1, 1568), 256, 0, stream>>>(attno, wp, projb, x1, x, 192, 192);
    ln_kernel<0><<<2048, 256, 0, stream>>>(x1, n2g, n2b, hbuf);
    mlp_kernel<<<1568, 256, 0, stream>>>(hbuf, w1, fc1b, w2, fc2b, (float*)d_out);
}